// Round 1
// baseline (915.786 us; speedup 1.0000x reference)
//
#include <hip/hip_runtime.h>
#include <hip/hip_bf16.h>
#include <cstdint>

#define N_BATCH 2
#define C_IN 256
#define DYN_CH 34
#define CLS_CH 720
#define NUM_CLASSES 80
#define SPLITK 4

// ---------------------------------------------------------------- K1: reg 1x1
__global__ __launch_bounds__(256) void reg_conv1x1(
    const float* __restrict__ x, const float* __restrict__ w,
    float* __restrict__ out, int P) {
  int p = blockIdx.x * 256 + threadIdx.x;
  int n = blockIdx.y;
  if (p >= P) return;
  float a0 = 0.f, a1 = 0.f, a2 = 0.f, a3 = 0.f;
  const float* xp = x + (size_t)n * C_IN * P + p;
  for (int c = 0; c < C_IN; ++c) {
    float v = xp[(size_t)c * P];
    a0 += v * w[c];
    a1 += v * w[256 + c];
    a2 += v * w[512 + c];
    a3 += v * w[768 + c];
  }
  float* op = out + (size_t)n * 4 * P + p;
  op[0] = a0; op[(size_t)P] = a1; op[(size_t)2 * P] = a2; op[(size_t)3 * P] = a3;
}

// ------------------------------------------------- transpose cls_w -> (256,720)
__global__ __launch_bounds__(256) void transpose_w(
    const float* __restrict__ w, float* __restrict__ wt) {
  int i = blockIdx.x * 256 + threadIdx.x;
  if (i >= CLS_CH * C_IN) return;
  int o = i / C_IN, c = i % C_IN;
  wt[c * CLS_CH + o] = w[i];
}

// ------------------------------------- K2: cls 1x1 as SGEMM -> bf16 map (N,P,720)
#define TM 128
#define TN 128
#define BK 8
__global__ __launch_bounds__(256) void cls_gemm(
    const float* __restrict__ x, const float* __restrict__ wt,
    __hip_bfloat16* __restrict__ out, int P) {
  __shared__ float As[BK][TM];
  __shared__ float Bs[BK][TN];
  int n = blockIdx.z;
  int m0 = blockIdx.x * TM;
  int o0 = blockIdx.y * TN;
  int tid = threadIdx.x;
  int tx = tid % 16;   // out-channel dir
  int ty = tid / 16;   // pixel dir
  float acc[8][8] = {};
  const float* xn = x + (size_t)n * C_IN * P;
  for (int kb = 0; kb < C_IN; kb += BK) {
#pragma unroll
    for (int l = 0; l < 4; ++l) {
      int idx = tid + l * 256;
      int kc = idx / TM, mm = idx % TM;
      int p = m0 + mm;
      As[kc][mm] = (p < P) ? xn[(size_t)(kb + kc) * P + p] : 0.f;
    }
#pragma unroll
    for (int l = 0; l < 4; ++l) {
      int idx = tid + l * 256;
      int kc = idx / TN, oo = idx % TN;
      int o = o0 + oo;
      Bs[kc][oo] = (o < CLS_CH) ? wt[(size_t)(kb + kc) * CLS_CH + o] : 0.f;
    }
    __syncthreads();
#pragma unroll
    for (int kc = 0; kc < BK; ++kc) {
      float4 a0 = *(const float4*)&As[kc][ty * 8];
      float4 a1 = *(const float4*)&As[kc][ty * 8 + 4];
      float4 b0 = *(const float4*)&Bs[kc][tx * 8];
      float4 b1 = *(const float4*)&Bs[kc][tx * 8 + 4];
      float a[8] = {a0.x, a0.y, a0.z, a0.w, a1.x, a1.y, a1.z, a1.w};
      float b[8] = {b0.x, b0.y, b0.z, b0.w, b1.x, b1.y, b1.z, b1.w};
#pragma unroll
      for (int i = 0; i < 8; ++i)
#pragma unroll
        for (int j = 0; j < 8; ++j) acc[i][j] += a[i] * b[j];
    }
    __syncthreads();
  }
#pragma unroll
  for (int i = 0; i < 8; ++i) {
    int p = m0 + ty * 8 + i;
    if (p >= P) continue;
    __hip_bfloat16* op = out + ((size_t)n * P + p) * CLS_CH;
#pragma unroll
    for (int j = 0; j < 8; ++j) {
      int o = o0 + tx * 8 + j;
      if (o < CLS_CH) op[o] = __float2bfloat16(acc[i][j]);
    }
  }
}

// -------------------------------------------- K3: dyn conv3x3 (split-K partials)
__global__ __launch_bounds__(256) void dyn_conv3x3(
    const float* __restrict__ x, const float* __restrict__ w,
    float* __restrict__ part, int H, int W, int P) {
  int p = blockIdx.x * 256 + threadIdx.x;
  int s = blockIdx.y;
  int n = blockIdx.z;
  if (p >= P) return;
  int yy = p / W, xx = p % W;
  float acc[DYN_CH];
#pragma unroll
  for (int o = 0; o < DYN_CH; ++o) acc[o] = 0.f;
  const int CK = C_IN / SPLITK;
  int c0 = s * CK;
  const float* xb = x + (size_t)n * C_IN * P;
  for (int c = c0; c < c0 + CK; ++c) {
    const float* xc = xb + (size_t)c * P;
    float tap[9];
#pragma unroll
    for (int dy = 0; dy < 3; ++dy)
#pragma unroll
      for (int dx = 0; dx < 3; ++dx) {
        int y2 = yy + dy - 1, x2 = xx + dx - 1;
        tap[dy * 3 + dx] =
            (y2 >= 0 && y2 < H && x2 >= 0 && x2 < W) ? xc[y2 * W + x2] : 0.f;
      }
    const float* wc = w + (size_t)c * 9;
#pragma unroll
    for (int o = 0; o < DYN_CH; ++o) {
      const float* wo = wc + (size_t)o * C_IN * 9;
      float a = acc[o];
#pragma unroll
      for (int k = 0; k < 9; ++k) a += tap[k] * wo[k];
      acc[o] = a;
    }
  }
  float* pp = part + (((size_t)s * N_BATCH + n) * P + p) * DYN_CH;
#pragma unroll
  for (int o = 0; o < DYN_CH; ++o) pp[o] = acc[o];
}

// ------------------------------------------------------------ bilinear helper
__device__ __forceinline__ float bilin(const float* __restrict__ f, float px,
                                       float py, int Wm, int Hm) {
  float xc = fminf(fmaxf(px, 0.f), (float)(Wm - 1));
  float yc = fminf(fmaxf(py, 0.f), (float)(Hm - 1));
  float x0f = floorf(xc), y0f = floorf(yc);
  float fx = xc - x0f, fy = yc - y0f;
  int x0 = (int)x0f, y0 = (int)y0f;
  int x1 = min(x0 + 1, Wm - 1), y1 = min(y0 + 1, Hm - 1);
  float v00 = f[y0 * Wm + x0], v01 = f[y0 * Wm + x1];
  float v10 = f[y1 * Wm + x0], v11 = f[y1 * Wm + x1];
  return v00 * (1.f - fx) * (1.f - fy) + v01 * fx * (1.f - fy) +
         v10 * (1.f - fx) * fy + v11 * fx * fy;
}

// ----------------------------------------------- K4a: per-pixel decode + sem pts
__global__ __launch_bounds__(256) void decode(
    const float* __restrict__ part, const float* __restrict__ dyn_b,
    const float* __restrict__ anchor, const float* __restrict__ regmap_hi,
    const float* __restrict__ regmap_lo, float* __restrict__ out_coarse,
    float* __restrict__ out_regbox, float* __restrict__ sem_ws, int H, int W,
    int P, int level) {
  int p = blockIdx.x * 256 + threadIdx.x;
  int n = blockIdx.y;
  if (p >= P) return;
  float pr[DYN_CH];
#pragma unroll
  for (int o = 0; o < DYN_CH; ++o) pr[o] = dyn_b[o];
#pragma unroll
  for (int s = 0; s < SPLITK; ++s) {
    const float* pp = part + (((size_t)s * N_BATCH + n) * P + p) * DYN_CH;
#pragma unroll
    for (int o = 0; o < DYN_CH; ++o) pr[o] += pp[o];
  }
  const float* an = anchor + (size_t)n * 4 * P + p;
  float cb[4];
#pragma unroll
  for (int k = 0; k < 4; ++k) cb[k] = an[(size_t)k * P] + pr[k];
  float* oc = out_coarse + (size_t)n * 4 * P + p;
#pragma unroll
  for (int k = 0; k < 4; ++k) oc[(size_t)k * P] = cb[k];

  float thr_y = (cb[3] - cb[1]) * 0.25f;  // (y2-y1)/2 * RATIO
  float thr_x = (cb[2] - cb[0]) * 0.25f;
  float bo[4];
#pragma unroll
  for (int j = 0; j < 4; ++j) {
    float thr = (j & 1) ? thr_x : thr_y;
    float b = pr[4 + j];
    float extra = fmaxf(b - thr, 0.f) + fminf(b + thr, 0.f);
    bo[j] = b - extra;
  }
  float cx = 0.5f * (cb[0] + cb[2]);
  float cy = 0.5f * (cb[1] + cb[3]);
  float bp[8] = {cb[0], cy + bo[0], cx + bo[1], cb[1],
                 cb[2], cy + bo[2], cx + bo[3], cb[3]};

  float rb[4];
  const float* rh = regmap_hi + (size_t)n * 4 * P;
  const float* rl = regmap_lo + (size_t)n * 4 * (100 * 152);
#pragma unroll
  for (int pt = 0; pt < 4; ++pt) {
    float hi = bilin(rh + (size_t)pt * P, bp[2 * pt], bp[2 * pt + 1], W, H);
    float val;
    if (level == 0) {
      val = hi;
    } else {
      float lo = 0.5f * bilin(rl + (size_t)pt * (100 * 152), bp[2 * pt] * 2.f,
                              bp[2 * pt + 1] * 2.f, 152, 100);
      float e0 = pr[26 + 2 * pt], e1 = pr[26 + 2 * pt + 1];
      float m = fmaxf(e0, e1);
      float w0 = expf(e0 - m), w1 = expf(e1 - m);
      val = (lo * w0 + hi * w1) / (w0 + w1);
    }
    rb[pt] = val;
  }
  float* orb = out_regbox + (size_t)n * 4 * P + p;
  orb[0] = bp[0] + rb[0];
  orb[(size_t)P] = bp[3] + rb[1];
  orb[(size_t)2 * P] = bp[4] + rb[2];
  orb[(size_t)3 * P] = bp[7] + rb[3];

  // sem points: (x1,y1)(x1,cy)(x1,y2)(cx,y1)(cx,cy)(cx,y2)(x2,y1)(x2,cy)(x2,y2)
  float sx[9] = {cb[0], cb[0], cb[0], cx, cx, cx, cb[2], cb[2], cb[2]};
  float sy[9] = {cb[1], cy, cb[3], cb[1], cy, cb[3], cb[1], cy, cb[3]};
  float* sw = sem_ws + ((size_t)n * P + p) * 18;
#pragma unroll
  for (int k = 0; k < 9; ++k) {
    sw[2 * k] = sx[k] + pr[8 + 2 * k];
    sw[2 * k + 1] = sy[k] + pr[8 + 2 * k + 1];
  }
}

// ----------------------------- K4b: cls gather (64 lanes/pixel over 80 classes)
__global__ __launch_bounds__(256) void cls_gather(
    const __hip_bfloat16* __restrict__ map, const float* __restrict__ sem_ws,
    const float* __restrict__ bias, float* __restrict__ out, int H, int W,
    int P) {
  int lane = threadIdx.x & 63;
  int pix = blockIdx.x * 4 + (threadIdx.x >> 6);
  int n = blockIdx.y;
  if (pix >= P) return;
  const float* sp = sem_ws + ((size_t)n * P + pix) * 18;
  float acc0 = 0.f, acc1 = 0.f;
  const __hip_bfloat16* mb = map + (size_t)n * P * CLS_CH;
#pragma unroll
  for (int pt = 0; pt < 9; ++pt) {
    float px = sp[2 * pt], py = sp[2 * pt + 1];
    float xc = fminf(fmaxf(px, 0.f), (float)(W - 1));
    float yc = fminf(fmaxf(py, 0.f), (float)(H - 1));
    float x0f = floorf(xc), y0f = floorf(yc);
    float fx = xc - x0f, fy = yc - y0f;
    int x0 = (int)x0f, y0 = (int)y0f;
    int x1 = min(x0 + 1, W - 1), y1 = min(y0 + 1, H - 1);
    float w00 = (1.f - fx) * (1.f - fy), w01 = fx * (1.f - fy);
    float w10 = (1.f - fx) * fy, w11 = fx * fy;
    const __hip_bfloat16* c00 = mb + (size_t)(y0 * W + x0) * CLS_CH + pt * 80;
    const __hip_bfloat16* c01 = mb + (size_t)(y0 * W + x1) * CLS_CH + pt * 80;
    const __hip_bfloat16* c10 = mb + (size_t)(y1 * W + x0) * CLS_CH + pt * 80;
    const __hip_bfloat16* c11 = mb + (size_t)(y1 * W + x1) * CLS_CH + pt * 80;
    acc0 += w00 * __bfloat162float(c00[lane]) + w01 * __bfloat162float(c01[lane]) +
            w10 * __bfloat162float(c10[lane]) + w11 * __bfloat162float(c11[lane]);
    if (lane < 16)
      acc1 += w00 * __bfloat162float(c00[lane + 64]) +
              w01 * __bfloat162float(c01[lane + 64]) +
              w10 * __bfloat162float(c10[lane + 64]) +
              w11 * __bfloat162float(c11[lane + 64]);
  }
  float* on = out + (size_t)n * NUM_CLASSES * P + pix;
  on[(size_t)lane * P] = acc0 + bias[lane];
  if (lane < 16) on[(size_t)(lane + 64) * P] = acc1 + bias[lane + 64];
}

// ---------------------------------------------------------------------- launch
extern "C" void kernel_launch(void* const* d_in, const int* in_sizes, int n_in,
                              void* d_out, int out_size, void* d_ws,
                              size_t ws_size, hipStream_t stream) {
  const float* reg_feat0 = (const float*)d_in[0];
  const float* reg_feat1 = (const float*)d_in[1];
  const float* cls_feat0 = (const float*)d_in[2];
  const float* cls_feat1 = (const float*)d_in[3];
  const float* anchor0 = (const float*)d_in[4];
  const float* anchor1 = (const float*)d_in[5];
  const float* dyn_w = (const float*)d_in[6];
  const float* dyn_b = (const float*)d_in[7];
  const float* reg_w = (const float*)d_in[8];
  const float* cls_w = (const float*)d_in[9];
  const float* cls_b = (const float*)d_in[10];

  const int P0 = 15200, P1 = 3800;
  float* out = (float*)d_out;
  float* out_cls0 = out;
  float* out_cls1 = out_cls0 + (size_t)N_BATCH * NUM_CLASSES * P0;
  float* out_coarse0 = out_cls1 + (size_t)N_BATCH * NUM_CLASSES * P1;
  float* out_coarse1 = out_coarse0 + (size_t)N_BATCH * 4 * P0;
  float* out_reg0 = out_coarse1 + (size_t)N_BATCH * 4 * P1;
  float* out_reg1 = out_reg0 + (size_t)N_BATCH * 4 * P0;

  // workspace layout (floats first, bf16 cls_map last; levels share buffers)
  float* wsf = (float*)d_ws;
  float* regmap0 = wsf;                          // 2*4*15200
  float* regmap1 = regmap0 + 121600;             // 2*4*3800
  float* wt = regmap1 + 30400;                   // 256*720
  float* partb = wt + 184320;                    // 4*2*15200*34
  float* semb = partb + (size_t)SPLITK * N_BATCH * 15200 * DYN_CH;  // 2*15200*18
  __hip_bfloat16* clsmap = (__hip_bfloat16*)(semb + (size_t)N_BATCH * 15200 * 18);

  hipLaunchKernelGGL(reg_conv1x1, dim3((P0 + 255) / 256, N_BATCH), dim3(256), 0,
                     stream, reg_feat0, reg_w, regmap0, P0);
  hipLaunchKernelGGL(reg_conv1x1, dim3((P1 + 255) / 256, N_BATCH), dim3(256), 0,
                     stream, reg_feat1, reg_w, regmap1, P1);
  hipLaunchKernelGGL(transpose_w, dim3((CLS_CH * C_IN + 255) / 256), dim3(256),
                     0, stream, cls_w, wt);

  // level 0
  hipLaunchKernelGGL(dyn_conv3x3, dim3((P0 + 255) / 256, SPLITK, N_BATCH),
                     dim3(256), 0, stream, reg_feat0, dyn_w, partb, 100, 152, P0);
  hipLaunchKernelGGL(cls_gemm, dim3((P0 + TM - 1) / TM, (CLS_CH + TN - 1) / TN, N_BATCH),
                     dim3(256), 0, stream, cls_feat0, wt, clsmap, P0);
  hipLaunchKernelGGL(decode, dim3((P0 + 255) / 256, N_BATCH), dim3(256), 0,
                     stream, partb, dyn_b, anchor0, regmap0, regmap0,
                     out_coarse0, out_reg0, semb, 100, 152, P0, 0);
  hipLaunchKernelGGL(cls_gather, dim3((P0 + 3) / 4, N_BATCH), dim3(256), 0,
                     stream, clsmap, semb, cls_b, out_cls0, 100, 152, P0);

  // level 1 (reuses partb/semb/clsmap)
  hipLaunchKernelGGL(dyn_conv3x3, dim3((P1 + 255) / 256, SPLITK, N_BATCH),
                     dim3(256), 0, stream, reg_feat1, dyn_w, partb, 50, 76, P1);
  hipLaunchKernelGGL(cls_gemm, dim3((P1 + TM - 1) / TM, (CLS_CH + TN - 1) / TN, N_BATCH),
                     dim3(256), 0, stream, cls_feat1, wt, clsmap, P1);
  hipLaunchKernelGGL(decode, dim3((P1 + 255) / 256, N_BATCH), dim3(256), 0,
                     stream, partb, dyn_b, anchor1, regmap1, regmap0,
                     out_coarse1, out_reg1, semb, 50, 76, P1, 1);
  hipLaunchKernelGGL(cls_gather, dim3((P1 + 3) / 4, N_BATCH), dim3(256), 0,
                     stream, clsmap, semb, cls_b, out_cls1, 50, 76, P1);
}

// Round 2
// 689.125 us; speedup vs baseline: 1.3289x; 1.3289x over previous
//
#include <hip/hip_runtime.h>
#include <hip/hip_bf16.h>
#include <cstdint>

#define N_BATCH 2
#define C_IN 256
#define DYN_CH 34
#define CLS_CH 720
#define NUM_CLASSES 80
#define SPLITK 4

typedef __attribute__((ext_vector_type(8))) short short8;   // 8 bf16
typedef __attribute__((ext_vector_type(4))) float f32x4;

typedef const unsigned int __attribute__((address_space(1)))* gas1_t;
typedef unsigned int __attribute__((address_space(3)))* las3_t;

__device__ __forceinline__ void async_ld16(const void* g, void* l) {
  __builtin_amdgcn_global_load_lds((gas1_t)g, (las3_t)l, 16, 0, 0);
}

// ---------------------------------------------------------------- K1: reg 1x1
__global__ __launch_bounds__(256) void reg_conv1x1(
    const float* __restrict__ x, const float* __restrict__ w,
    float* __restrict__ out, int P) {
  int p = blockIdx.x * 256 + threadIdx.x;
  int n = blockIdx.y;
  if (p >= P) return;
  float a0 = 0.f, a1 = 0.f, a2 = 0.f, a3 = 0.f;
  const float* xp = x + (size_t)n * C_IN * P + p;
  for (int c = 0; c < C_IN; ++c) {
    float v = xp[(size_t)c * P];
    a0 += v * w[c];
    a1 += v * w[256 + c];
    a2 += v * w[512 + c];
    a3 += v * w[768 + c];
  }
  float* op = out + (size_t)n * 4 * P + p;
  op[0] = a0; op[(size_t)P] = a1; op[(size_t)2 * P] = a2; op[(size_t)3 * P] = a3;
}

// --------------------------- pack A: fp32 (N,C,P) -> bf16 tiled [mtile][kcg][row]
// unit u (16B = 8 bf16 along K): mtile = u/8192, kcg = (u%8192)/256, row = u%256
__global__ __launch_bounds__(256) void pack_a(
    const float* __restrict__ x, __hip_bfloat16* __restrict__ ap, int P,
    int Mtot) {
  size_t u = (size_t)blockIdx.x * 256 + threadIdx.x;
  int mtile = (int)(u >> 13);
  int rem = (int)(u & 8191);
  int kcg = rem >> 8;
  int row = rem & 255;
  int g = mtile * 256 + row;
  __hip_bfloat16 tmp[8];
  if (g < Mtot) {
    int n = g / P, p = g % P;
    const float* xb = x + (size_t)n * C_IN * P + (size_t)(kcg * 8) * P + p;
#pragma unroll
    for (int c = 0; c < 8; ++c) tmp[c] = __float2bfloat16(xb[(size_t)c * P]);
  } else {
#pragma unroll
    for (int c = 0; c < 8; ++c) tmp[c] = __float2bfloat16(0.f);
  }
  *(uint4*)(ap + u * 8) = *(const uint4*)tmp;
}

// --------------------------- pack B: cls_w (720,256) -> bf16 [ntile][kcg][och]
__global__ __launch_bounds__(256) void pack_b(
    const float* __restrict__ w, __hip_bfloat16* __restrict__ bp) {
  int u = blockIdx.x * 256 + threadIdx.x;  // 23040 units
  if (u >= 9 * 32 * 80) return;
  int ntile = u / 2560;
  int rem = u % 2560;
  int kcg = rem / 80;
  int ochl = rem % 80;
  int och = ntile * 80 + ochl;
  const float* wr = w + (size_t)och * C_IN + kcg * 8;
  __hip_bfloat16 tmp[8];
#pragma unroll
  for (int c = 0; c < 8; ++c) tmp[c] = __float2bfloat16(wr[c]);
  *(uint4*)(bp + (size_t)u * 8) = *(const uint4*)tmp;
}

// ------------------------- K2: cls 1x1 as bf16 MFMA GEMM -> bf16 map (M,720)
// block: 256 thr = 4 waves stacked in M; tile 256M x 80N, BK=32, K=256
__global__ __launch_bounds__(256) void cls_gemm_mfma(
    const uint4* __restrict__ Ap, const uint4* __restrict__ Bp,
    __hip_bfloat16* __restrict__ out, int Mtot) {
  __shared__ uint4 Ash[1024];  // [kc 0..3][row 0..255]
  __shared__ uint4 Bsh[320];   // [kc 0..3][och 0..79]
  int tid = threadIdx.x;
  int wave = tid >> 6;
  int lane = tid & 63;
  int l15 = lane & 15;
  int kq = lane >> 4;
  int mtile = blockIdx.x;
  int ntile = blockIdx.y;

  const uint4* Ab = Ap + (size_t)mtile * 8192;         // 32 kcg x 256 rows
  const uint4* Bb = Bp + (size_t)ntile * 2560;         // 32 kcg x 80 och

  f32x4 acc[4][5];
#pragma unroll
  for (int i = 0; i < 4; ++i)
#pragma unroll
    for (int j = 0; j < 5; ++j) acc[i][j] = (f32x4)0.f;

  for (int kb = 0; kb < 8; ++kb) {
    // stage A: 16 chunks of 64 units; wave w does chunks w*4..w*4+3
    const uint4* Aslab = Ab + kb * 1024;
#pragma unroll
    for (int i = 0; i < 4; ++i) {
      int j = wave * 4 + i;
      async_ld16(Aslab + j * 64 + lane, &Ash[j * 64]);
    }
    // stage B: 5 chunks of 64 units
    const uint4* Bslab = Bb + kb * 320;
    for (int j = wave; j < 5; j += 4) {
      async_ld16(Bslab + j * 64 + lane, &Bsh[j * 64]);
    }
    __syncthreads();

    short8 a[4], b[5];
    const uint4* Ar = &Ash[kq * 256 + wave * 64 + l15];
#pragma unroll
    for (int mi = 0; mi < 4; ++mi) a[mi] = *(const short8*)&Ar[mi * 16];
    const uint4* Br = &Bsh[kq * 80 + l15];
#pragma unroll
    for (int ni = 0; ni < 5; ++ni) b[ni] = *(const short8*)&Br[ni * 16];
#pragma unroll
    for (int mi = 0; mi < 4; ++mi)
#pragma unroll
      for (int ni = 0; ni < 5; ++ni)
        acc[mi][ni] = __builtin_amdgcn_mfma_f32_16x16x32_bf16(
            a[mi], b[ni], acc[mi][ni], 0, 0, 0);
    __syncthreads();
  }

  // epilogue: D row = kq*4 + r (M dir), col = l15 (N dir)
  int gbase = mtile * 256 + wave * 64;
#pragma unroll
  for (int mi = 0; mi < 4; ++mi) {
#pragma unroll
    for (int r = 0; r < 4; ++r) {
      int g = gbase + mi * 16 + kq * 4 + r;
      if (g >= Mtot) continue;
      __hip_bfloat16* orow = out + (size_t)g * CLS_CH + ntile * 80 + l15;
#pragma unroll
      for (int ni = 0; ni < 5; ++ni)
        orow[ni * 16] = __float2bfloat16(acc[mi][ni][r]);
    }
  }
}

// -------------------------------------------- K3: dyn conv3x3 (split-K partials)
__global__ __launch_bounds__(256) void dyn_conv3x3(
    const float* __restrict__ x, const float* __restrict__ w,
    float* __restrict__ part, int H, int W, int P) {
  int p = blockIdx.x * 256 + threadIdx.x;
  int s = blockIdx.y;
  int n = blockIdx.z;
  if (p >= P) return;
  int yy = p / W, xx = p % W;
  float acc[DYN_CH];
#pragma unroll
  for (int o = 0; o < DYN_CH; ++o) acc[o] = 0.f;
  const int CK = C_IN / SPLITK;
  int c0 = s * CK;
  const float* xb = x + (size_t)n * C_IN * P;
  for (int c = c0; c < c0 + CK; ++c) {
    const float* xc = xb + (size_t)c * P;
    float tap[9];
#pragma unroll
    for (int dy = 0; dy < 3; ++dy)
#pragma unroll
      for (int dx = 0; dx < 3; ++dx) {
        int y2 = yy + dy - 1, x2 = xx + dx - 1;
        tap[dy * 3 + dx] =
            (y2 >= 0 && y2 < H && x2 >= 0 && x2 < W) ? xc[y2 * W + x2] : 0.f;
      }
    const float* wc = w + (size_t)c * 9;
#pragma unroll
    for (int o = 0; o < DYN_CH; ++o) {
      const float* wo = wc + (size_t)o * C_IN * 9;
      float a = acc[o];
#pragma unroll
      for (int k = 0; k < 9; ++k) a += tap[k] * wo[k];
      acc[o] = a;
    }
  }
  float* pp = part + (((size_t)s * N_BATCH + n) * P + p) * DYN_CH;
#pragma unroll
  for (int o = 0; o < DYN_CH; ++o) pp[o] = acc[o];
}

// ------------------------------------------------------------ bilinear helper
__device__ __forceinline__ float bilin(const float* __restrict__ f, float px,
                                       float py, int Wm, int Hm) {
  float xc = fminf(fmaxf(px, 0.f), (float)(Wm - 1));
  float yc = fminf(fmaxf(py, 0.f), (float)(Hm - 1));
  float x0f = floorf(xc), y0f = floorf(yc);
  float fx = xc - x0f, fy = yc - y0f;
  int x0 = (int)x0f, y0 = (int)y0f;
  int x1 = min(x0 + 1, Wm - 1), y1 = min(y0 + 1, Hm - 1);
  float v00 = f[y0 * Wm + x0], v01 = f[y0 * Wm + x1];
  float v10 = f[y1 * Wm + x0], v11 = f[y1 * Wm + x1];
  return v00 * (1.f - fx) * (1.f - fy) + v01 * fx * (1.f - fy) +
         v10 * (1.f - fx) * fy + v11 * fx * fy;
}

// ----------------------------------------------- K4a: per-pixel decode + sem pts
__global__ __launch_bounds__(256) void decode(
    const float* __restrict__ part, const float* __restrict__ dyn_b,
    const float* __restrict__ anchor, const float* __restrict__ regmap_hi,
    const float* __restrict__ regmap_lo, float* __restrict__ out_coarse,
    float* __restrict__ out_regbox, float* __restrict__ sem_ws, int H, int W,
    int P, int level) {
  int p = blockIdx.x * 256 + threadIdx.x;
  int n = blockIdx.y;
  if (p >= P) return;
  float pr[DYN_CH];
#pragma unroll
  for (int o = 0; o < DYN_CH; ++o) pr[o] = dyn_b[o];
#pragma unroll
  for (int s = 0; s < SPLITK; ++s) {
    const float* pp = part + (((size_t)s * N_BATCH + n) * P + p) * DYN_CH;
#pragma unroll
    for (int o = 0; o < DYN_CH; ++o) pr[o] += pp[o];
  }
  const float* an = anchor + (size_t)n * 4 * P + p;
  float cb[4];
#pragma unroll
  for (int k = 0; k < 4; ++k) cb[k] = an[(size_t)k * P] + pr[k];
  float* oc = out_coarse + (size_t)n * 4 * P + p;
#pragma unroll
  for (int k = 0; k < 4; ++k) oc[(size_t)k * P] = cb[k];

  float thr_y = (cb[3] - cb[1]) * 0.25f;
  float thr_x = (cb[2] - cb[0]) * 0.25f;
  float bo[4];
#pragma unroll
  for (int j = 0; j < 4; ++j) {
    float thr = (j & 1) ? thr_x : thr_y;
    float b = pr[4 + j];
    float extra = fmaxf(b - thr, 0.f) + fminf(b + thr, 0.f);
    bo[j] = b - extra;
  }
  float cx = 0.5f * (cb[0] + cb[2]);
  float cy = 0.5f * (cb[1] + cb[3]);
  float bp[8] = {cb[0], cy + bo[0], cx + bo[1], cb[1],
                 cb[2], cy + bo[2], cx + bo[3], cb[3]};

  float rb[4];
  const float* rh = regmap_hi + (size_t)n * 4 * P;
  const float* rl = regmap_lo + (size_t)n * 4 * (100 * 152);
#pragma unroll
  for (int pt = 0; pt < 4; ++pt) {
    float hi = bilin(rh + (size_t)pt * P, bp[2 * pt], bp[2 * pt + 1], W, H);
    float val;
    if (level == 0) {
      val = hi;
    } else {
      float lo = 0.5f * bilin(rl + (size_t)pt * (100 * 152), bp[2 * pt] * 2.f,
                              bp[2 * pt + 1] * 2.f, 152, 100);
      float e0 = pr[26 + 2 * pt], e1 = pr[26 + 2 * pt + 1];
      float m = fmaxf(e0, e1);
      float w0 = expf(e0 - m), w1 = expf(e1 - m);
      val = (lo * w0 + hi * w1) / (w0 + w1);
    }
    rb[pt] = val;
  }
  float* orb = out_regbox + (size_t)n * 4 * P + p;
  orb[0] = bp[0] + rb[0];
  orb[(size_t)P] = bp[3] + rb[1];
  orb[(size_t)2 * P] = bp[4] + rb[2];
  orb[(size_t)3 * P] = bp[7] + rb[3];

  float sx[9] = {cb[0], cb[0], cb[0], cx, cx, cx, cb[2], cb[2], cb[2]};
  float sy[9] = {cb[1], cy, cb[3], cb[1], cy, cb[3], cb[1], cy, cb[3]};
  float* sw = sem_ws + ((size_t)n * P + p) * 18;
#pragma unroll
  for (int k = 0; k < 9; ++k) {
    sw[2 * k] = sx[k] + pr[8 + 2 * k];
    sw[2 * k + 1] = sy[k] + pr[8 + 2 * k + 1];
  }
}

// ----------------------------- K4b: cls gather (64 lanes/pixel over 80 classes)
__global__ __launch_bounds__(256) void cls_gather(
    const __hip_bfloat16* __restrict__ map, const float* __restrict__ sem_ws,
    const float* __restrict__ bias, float* __restrict__ out, int H, int W,
    int P) {
  int lane = threadIdx.x & 63;
  int pix = blockIdx.x * 4 + (threadIdx.x >> 6);
  int n = blockIdx.y;
  if (pix >= P) return;
  const float* sp = sem_ws + ((size_t)n * P + pix) * 18;
  float acc0 = 0.f, acc1 = 0.f;
  const __hip_bfloat16* mb = map + (size_t)n * P * CLS_CH;
#pragma unroll
  for (int pt = 0; pt < 9; ++pt) {
    float px = sp[2 * pt], py = sp[2 * pt + 1];
    float xc = fminf(fmaxf(px, 0.f), (float)(W - 1));
    float yc = fminf(fmaxf(py, 0.f), (float)(H - 1));
    float x0f = floorf(xc), y0f = floorf(yc);
    float fx = xc - x0f, fy = yc - y0f;
    int x0 = (int)x0f, y0 = (int)y0f;
    int x1 = min(x0 + 1, W - 1), y1 = min(y0 + 1, H - 1);
    float w00 = (1.f - fx) * (1.f - fy), w01 = fx * (1.f - fy);
    float w10 = (1.f - fx) * fy, w11 = fx * fy;
    const __hip_bfloat16* c00 = mb + (size_t)(y0 * W + x0) * CLS_CH + pt * 80;
    const __hip_bfloat16* c01 = mb + (size_t)(y0 * W + x1) * CLS_CH + pt * 80;
    const __hip_bfloat16* c10 = mb + (size_t)(y1 * W + x0) * CLS_CH + pt * 80;
    const __hip_bfloat16* c11 = mb + (size_t)(y1 * W + x1) * CLS_CH + pt * 80;
    acc0 += w00 * __bfloat162float(c00[lane]) + w01 * __bfloat162float(c01[lane]) +
            w10 * __bfloat162float(c10[lane]) + w11 * __bfloat162float(c11[lane]);
    if (lane < 16)
      acc1 += w00 * __bfloat162float(c00[lane + 64]) +
              w01 * __bfloat162float(c01[lane + 64]) +
              w10 * __bfloat162float(c10[lane + 64]) +
              w11 * __bfloat162float(c11[lane + 64]);
  }
  float* on = out + (size_t)n * NUM_CLASSES * P + pix;
  on[(size_t)lane * P] = acc0 + bias[lane];
  if (lane < 16) on[(size_t)(lane + 64) * P] = acc1 + bias[lane + 64];
}

// ---------------------------------------------------------------------- launch
extern "C" void kernel_launch(void* const* d_in, const int* in_sizes, int n_in,
                              void* d_out, int out_size, void* d_ws,
                              size_t ws_size, hipStream_t stream) {
  const float* reg_feat0 = (const float*)d_in[0];
  const float* reg_feat1 = (const float*)d_in[1];
  const float* cls_feat0 = (const float*)d_in[2];
  const float* cls_feat1 = (const float*)d_in[3];
  const float* anchor0 = (const float*)d_in[4];
  const float* anchor1 = (const float*)d_in[5];
  const float* dyn_w = (const float*)d_in[6];
  const float* dyn_b = (const float*)d_in[7];
  const float* reg_w = (const float*)d_in[8];
  const float* cls_w = (const float*)d_in[9];
  const float* cls_b = (const float*)d_in[10];

  const int P0 = 15200, P1 = 3800;
  const int M0 = N_BATCH * P0;          // 30400
  const int M1 = N_BATCH * P1;          // 7600
  const int MT0 = (M0 + 255) / 256;     // 119
  const int MT1 = (M1 + 255) / 256;     // 30

  float* out = (float*)d_out;
  float* out_cls0 = out;
  float* out_cls1 = out_cls0 + (size_t)N_BATCH * NUM_CLASSES * P0;
  float* out_coarse0 = out_cls1 + (size_t)N_BATCH * NUM_CLASSES * P1;
  float* out_coarse1 = out_coarse0 + (size_t)N_BATCH * 4 * P0;
  float* out_reg0 = out_coarse1 + (size_t)N_BATCH * 4 * P1;
  float* out_reg1 = out_reg0 + (size_t)N_BATCH * 4 * P0;

  // ---- workspace layout (R region: Apack aliases partb; stream order keeps it safe)
  float* wsf = (float*)d_ws;
  float* regmap0 = wsf;                              // 121600 f
  float* regmap1 = regmap0 + 121600;                 // 30400 f
  float* semb = regmap1 + 30400;                     // 547200 f
  __hip_bfloat16* bpack = (__hip_bfloat16*)(semb + 547200);  // 92160 f
  float* Rreg = (float*)((char*)bpack + 368640);     // 4134400 f (partb | apack)
  float* partb = Rreg;
  __hip_bfloat16* apack = (__hip_bfloat16*)Rreg;
  __hip_bfloat16* clsmap = (__hip_bfloat16*)(Rreg + 4134400);

  hipLaunchKernelGGL(reg_conv1x1, dim3((P0 + 255) / 256, N_BATCH), dim3(256), 0,
                     stream, reg_feat0, reg_w, regmap0, P0);
  hipLaunchKernelGGL(reg_conv1x1, dim3((P1 + 255) / 256, N_BATCH), dim3(256), 0,
                     stream, reg_feat1, reg_w, regmap1, P1);
  hipLaunchKernelGGL(pack_b, dim3(90), dim3(256), 0, stream, cls_w, bpack);

  // ---- level 0: cls path first (apack lives in R), then dyn path (partb in R)
  hipLaunchKernelGGL(pack_a, dim3(MT0 * 32), dim3(256), 0, stream, cls_feat0,
                     apack, P0, M0);
  hipLaunchKernelGGL(cls_gemm_mfma, dim3(MT0, 9), dim3(256), 0, stream,
                     (const uint4*)apack, (const uint4*)bpack, clsmap, M0);
  hipLaunchKernelGGL(dyn_conv3x3, dim3((P0 + 255) / 256, SPLITK, N_BATCH),
                     dim3(256), 0, stream, reg_feat0, dyn_w, partb, 100, 152, P0);
  hipLaunchKernelGGL(decode, dim3((P0 + 255) / 256, N_BATCH), dim3(256), 0,
                     stream, partb, dyn_b, anchor0, regmap0, regmap0,
                     out_coarse0, out_reg0, semb, 100, 152, P0, 0);
  hipLaunchKernelGGL(cls_gather, dim3((P0 + 3) / 4, N_BATCH), dim3(256), 0,
                     stream, clsmap, semb, cls_b, out_cls0, 100, 152, P0);

  // ---- level 1
  hipLaunchKernelGGL(pack_a, dim3(MT1 * 32), dim3(256), 0, stream, cls_feat1,
                     apack, P1, M1);
  hipLaunchKernelGGL(cls_gemm_mfma, dim3(MT1, 9), dim3(256), 0, stream,
                     (const uint4*)apack, (const uint4*)bpack, clsmap, M1);
  hipLaunchKernelGGL(dyn_conv3x3, dim3((P1 + 255) / 256, SPLITK, N_BATCH),
                     dim3(256), 0, stream, reg_feat1, dyn_w, partb, 50, 76, P1);
  hipLaunchKernelGGL(decode, dim3((P1 + 255) / 256, N_BATCH), dim3(256), 0,
                     stream, partb, dyn_b, anchor1, regmap1, regmap0,
                     out_coarse1, out_reg1, semb, 50, 76, P1, 1);
  hipLaunchKernelGGL(cls_gather, dim3((P1 + 3) / 4, N_BATCH), dim3(256), 0,
                     stream, clsmap, semb, cls_b, out_cls1, 50, 76, P1);
}

// Round 3
// 357.970 us; speedup vs baseline: 2.5583x; 1.9251x over previous
//
#include <hip/hip_runtime.h>
#include <hip/hip_bf16.h>
#include <cstdint>

#define N_BATCH 2
#define C_IN 256
#define DYN_CH 34
#define CLS_CH 720
#define NUM_CLASSES 80
#define NCOMB 48   // 34 dyn + 4 reg + 10 pad, 3 MFMA n-tiles of 16

typedef __attribute__((ext_vector_type(8))) short short8;   // 8 bf16
typedef __attribute__((ext_vector_type(4))) float f32x4;

typedef const unsigned int __attribute__((address_space(1)))* gas1_t;
typedef unsigned int __attribute__((address_space(3)))* las3_t;

__device__ __forceinline__ void async_ld16(const void* g, void* l) {
  __builtin_amdgcn_global_load_lds((gas1_t)g, (las3_t)l, 16, 0, 0);
}

// --------------------------- pack A (cls): fp32 (N,C,P) -> bf16 tiled [mtile][kcg][row]
__global__ __launch_bounds__(256) void pack_a(
    const float* __restrict__ x, __hip_bfloat16* __restrict__ ap, int P,
    int Mtot) {
  size_t u = (size_t)blockIdx.x * 256 + threadIdx.x;
  int mtile = (int)(u >> 13);
  int rem = (int)(u & 8191);
  int kcg = rem >> 8;
  int row = rem & 255;
  int g = mtile * 256 + row;
  __hip_bfloat16 tmp[8];
  if (g < Mtot) {
    int n = g / P, p = g % P;
    const float* xb = x + (size_t)n * C_IN * P + (size_t)(kcg * 8) * P + p;
#pragma unroll
    for (int c = 0; c < 8; ++c) tmp[c] = __float2bfloat16(xb[(size_t)c * P]);
  } else {
#pragma unroll
    for (int c = 0; c < 8; ++c) tmp[c] = __float2bfloat16(0.f);
  }
  *(uint4*)(ap + u * 8) = *(const uint4*)tmp;
}

// --------------------------- pack row-major (reg): fp32 (N,C,P) -> bf16 [m][256]
__global__ __launch_bounds__(256) void pack_row(
    const float* __restrict__ x, __hip_bfloat16* __restrict__ rp, int P,
    int Mtot) {
  size_t u = (size_t)blockIdx.x * 256 + threadIdx.x;
  int mtile = (int)(u >> 13);
  int rem = (int)(u & 8191);
  int kcg = rem >> 8;
  int row = rem & 255;
  int m = mtile * 256 + row;
  if (m >= Mtot) return;
  int n = m / P, p = m % P;
  const float* xb = x + (size_t)n * C_IN * P + (size_t)(kcg * 8) * P + p;
  __hip_bfloat16 tmp[8];
#pragma unroll
  for (int c = 0; c < 8; ++c) tmp[c] = __float2bfloat16(xb[(size_t)c * P]);
  *((uint4*)rp + (size_t)m * 32 + kcg) = *(const uint4*)tmp;
}

// --------------------------- pack B (cls): cls_w (720,256) -> bf16 [ntile][kcg][och]
__global__ __launch_bounds__(256) void pack_b(
    const float* __restrict__ w, __hip_bfloat16* __restrict__ bp) {
  int u = blockIdx.x * 256 + threadIdx.x;
  if (u >= 9 * 32 * 80) return;
  int ntile = u / 2560;
  int rem = u % 2560;
  int kcg = rem / 80;
  int ochl = rem % 80;
  int och = ntile * 80 + ochl;
  const float* wr = w + (size_t)och * C_IN + kcg * 8;
  __hip_bfloat16 tmp[8];
#pragma unroll
  for (int c = 0; c < 8; ++c) tmp[c] = __float2bfloat16(wr[c]);
  *(uint4*)(bp + (size_t)u * 8) = *(const uint4*)tmp;
}

// -------- pack W (dyn 3x3 + reg 1x1 center-tap): -> bf16 swizzled [chunk j][n][slot s]
// k = tap*256 + c ; chunk j covers k in [j*128,(j+1)*128) = 16 units of 8ch.
// storage slot s holds k-unit (s ^ (n&7)) -> conflict-free ds_read_b128 later.
__global__ __launch_bounds__(256) void pack_w(
    const float* __restrict__ dyn_w, const float* __restrict__ reg_w,
    __hip_bfloat16* __restrict__ wp) {
  int u = blockIdx.x * 256 + threadIdx.x;  // 18*768 = 13824 units
  if (u >= 13824) return;
  int j = u / 768;
  int r = u % 768;
  int n = r / 16;
  int s = r % 16;
  int ku = j * 16 + (s ^ (n & 7));
  int k0 = ku * 8;
  int tap = k0 >> 8;
  int c0 = k0 & 255;
  __hip_bfloat16 tmp[8];
#pragma unroll
  for (int i = 0; i < 8; ++i) {
    int c = c0 + i;
    float v = 0.f;
    if (n < DYN_CH) v = dyn_w[((size_t)n * C_IN + c) * 9 + tap];
    else if (n < DYN_CH + 4 && tap == 4) v = reg_w[(size_t)(n - DYN_CH) * C_IN + c];
    tmp[i] = __float2bfloat16(v);
  }
  *(uint4*)(wp + (size_t)u * 8) = *(const uint4*)tmp;
}

// ------------------------- K2: cls 1x1 as bf16 MFMA GEMM -> bf16 map (M,720)
__global__ __launch_bounds__(256) void cls_gemm_mfma(
    const uint4* __restrict__ Ap, const uint4* __restrict__ Bp,
    __hip_bfloat16* __restrict__ out, int Mtot) {
  __shared__ uint4 Ash[1024];
  __shared__ uint4 Bsh[320];
  int tid = threadIdx.x;
  int wave = tid >> 6;
  int lane = tid & 63;
  int l15 = lane & 15;
  int kq = lane >> 4;
  int mtile = blockIdx.x;
  int ntile = blockIdx.y;

  const uint4* Ab = Ap + (size_t)mtile * 8192;
  const uint4* Bb = Bp + (size_t)ntile * 2560;

  f32x4 acc[4][5];
#pragma unroll
  for (int i = 0; i < 4; ++i)
#pragma unroll
    for (int j = 0; j < 5; ++j) acc[i][j] = (f32x4)0.f;

  for (int kb = 0; kb < 8; ++kb) {
    const uint4* Aslab = Ab + kb * 1024;
#pragma unroll
    for (int i = 0; i < 4; ++i) {
      int j = wave * 4 + i;
      async_ld16(Aslab + j * 64 + lane, &Ash[j * 64]);
    }
    const uint4* Bslab = Bb + kb * 320;
    for (int j = wave; j < 5; j += 4) {
      async_ld16(Bslab + j * 64 + lane, &Bsh[j * 64]);
    }
    __syncthreads();

    short8 a[4], b[5];
    const uint4* Ar = &Ash[kq * 256 + wave * 64 + l15];
#pragma unroll
    for (int mi = 0; mi < 4; ++mi) a[mi] = *(const short8*)&Ar[mi * 16];
    const uint4* Br = &Bsh[kq * 80 + l15];
#pragma unroll
    for (int ni = 0; ni < 5; ++ni) b[ni] = *(const short8*)&Br[ni * 16];
#pragma unroll
    for (int mi = 0; mi < 4; ++mi)
#pragma unroll
      for (int ni = 0; ni < 5; ++ni)
        acc[mi][ni] = __builtin_amdgcn_mfma_f32_16x16x32_bf16(
            a[mi], b[ni], acc[mi][ni], 0, 0, 0);
    __syncthreads();
  }

  int gbase = mtile * 256 + wave * 64;
#pragma unroll
  for (int mi = 0; mi < 4; ++mi) {
#pragma unroll
    for (int r = 0; r < 4; ++r) {
      int g = gbase + mi * 16 + kq * 4 + r;
      if (g >= Mtot) continue;
      __hip_bfloat16* orow = out + (size_t)g * CLS_CH + ntile * 80 + l15;
#pragma unroll
      for (int ni = 0; ni < 5; ++ni)
        orow[ni * 16] = __float2bfloat16(acc[mi][ni][r]);
    }
  }
}

// ---------- K3: dyn3x3 + reg1x1 fused implicit-GEMM MFMA, split-K=3 (tap triples)
// A: rpack [m][256] bf16, direct global loads (tap => row offset, oob => 0)
// B: wpack chunks staged to LDS via global_load_lds (linear, swizzle pre-baked)
// out: part [seg][Mtot][48] fp32
__global__ __launch_bounds__(256) void dyn_reg_conv_mfma(
    const uint4* __restrict__ rp, const uint4* __restrict__ wp,
    float* __restrict__ part, int Mtot, int P, int W, int H) {
  __shared__ uint4 Bs[768];  // 48 n x 16 units (12 KB)
  int tid = threadIdx.x;
  int wave = tid >> 6;
  int lane = tid & 63;
  int l15 = lane & 15;
  int kq = lane >> 4;
  int seg = blockIdx.y;

  int m = blockIdx.x * 64 + wave * 16 + l15;
  bool mval = (m < Mtot);
  int mc = mval ? m : 0;
  int n = mc / P;
  int rem = mc - n * P;
  int y = rem / W;
  int x = rem - y * W;

  f32x4 acc[3];
#pragma unroll
  for (int i = 0; i < 3; ++i) acc[i] = (f32x4)0.f;

  for (int jj = 0; jj < 6; ++jj) {
    int j = seg * 6 + jj;
    // stage B chunk j (768 units, 3 per thread, linear)
    const uint4* wsrc = wp + (size_t)j * 768 + wave * 192;
#pragma unroll
    for (int i = 0; i < 3; ++i)
      async_ld16(wsrc + i * 64 + lane, &Bs[wave * 192 + i * 64]);

    // A fragments (global, no LDS)
    int tap = j >> 1;
    int cb8 = (j & 1) * 16;  // unit offset of c_base within row
    int dy = tap / 3 - 1, dx = tap % 3 - 1;
    int sy = y + dy, sx = x + dx;
    bool val = mval && ((unsigned)sy < (unsigned)H) && ((unsigned)sx < (unsigned)W);
    size_t srow = (size_t)(m + dy * W + dx);
    uint4 a[4];
#pragma unroll
    for (int t = 0; t < 4; ++t) {
      uint4 v = {0u, 0u, 0u, 0u};
      if (val) v = rp[srow * 32 + cb8 + t * 4 + kq];
      a[t] = v;
    }
    __syncthreads();
#pragma unroll
    for (int t = 0; t < 4; ++t) {
#pragma unroll
      for (int ni = 0; ni < 3; ++ni) {
        int nn = ni * 16 + l15;
        short8 bf = *(const short8*)&Bs[nn * 16 + ((t * 4 + kq) ^ (nn & 7))];
        acc[ni] = __builtin_amdgcn_mfma_f32_16x16x32_bf16(
            *(short8*)&a[t], bf, acc[ni], 0, 0, 0);
      }
    }
    __syncthreads();
  }

  // epilogue: C row = kq*4+r (pixel), col = l15 (out-ch)
  int mrow = blockIdx.x * 64 + wave * 16 + kq * 4;
#pragma unroll
  for (int r = 0; r < 4; ++r) {
    int mm = mrow + r;
    if (mm >= Mtot) continue;
    float* dst = part + ((size_t)seg * Mtot + mm) * NCOMB + l15;
#pragma unroll
    for (int ni = 0; ni < 3; ++ni) dst[ni * 16] = acc[ni][r];
  }
}

// -------------------- bilinear sample of combined-map channel (sums 3 K-segments)
__device__ __forceinline__ float samp48(const float* __restrict__ part,
                                        int Mtot, int nbase, int W, int H,
                                        float px, float py, int ch) {
  float xc = fminf(fmaxf(px, 0.f), (float)(W - 1));
  float yc = fminf(fmaxf(py, 0.f), (float)(H - 1));
  float x0f = floorf(xc), y0f = floorf(yc);
  float fx = xc - x0f, fy = yc - y0f;
  int x0 = (int)x0f, y0 = (int)y0f;
  int x1 = min(x0 + 1, W - 1), y1 = min(y0 + 1, H - 1);
  size_t m00 = (size_t)(nbase + y0 * W + x0);
  size_t m01 = (size_t)(nbase + y0 * W + x1);
  size_t m10 = (size_t)(nbase + y1 * W + x0);
  size_t m11 = (size_t)(nbase + y1 * W + x1);
  float v00 = 0.f, v01 = 0.f, v10 = 0.f, v11 = 0.f;
#pragma unroll
  for (int s = 0; s < 3; ++s) {
    size_t off = (size_t)s * Mtot;
    v00 += part[(off + m00) * NCOMB + ch];
    v01 += part[(off + m01) * NCOMB + ch];
    v10 += part[(off + m10) * NCOMB + ch];
    v11 += part[(off + m11) * NCOMB + ch];
  }
  return v00 * (1.f - fx) * (1.f - fy) + v01 * fx * (1.f - fy) +
         v10 * (1.f - fx) * fy + v11 * fx * fy;
}

// ----------------------------------------------- K4a: per-pixel decode + sem pts
__global__ __launch_bounds__(256) void decode(
    const float* __restrict__ part, const float* __restrict__ part_lo,
    const float* __restrict__ dyn_b, const float* __restrict__ anchor,
    float* __restrict__ out_coarse, float* __restrict__ out_regbox,
    float* __restrict__ sem_ws, int Mtot, int MtotLo, int H, int W, int P,
    int level) {
  int p = blockIdx.x * 256 + threadIdx.x;
  int n = blockIdx.y;
  if (p >= P) return;
  int m = n * P + p;
  float pr[38];
  {
    const float* p0 = part + (size_t)m * NCOMB;
    const float* p1 = part + ((size_t)Mtot + m) * NCOMB;
    const float* p2 = part + ((size_t)2 * Mtot + m) * NCOMB;
#pragma unroll
    for (int o = 0; o < 38; ++o) pr[o] = p0[o] + p1[o] + p2[o];
#pragma unroll
    for (int o = 0; o < DYN_CH; ++o) pr[o] += dyn_b[o];
  }
  const float* an = anchor + (size_t)n * 4 * P + p;
  float cb[4];
#pragma unroll
  for (int k = 0; k < 4; ++k) cb[k] = an[(size_t)k * P] + pr[k];
  float* oc = out_coarse + (size_t)n * 4 * P + p;
#pragma unroll
  for (int k = 0; k < 4; ++k) oc[(size_t)k * P] = cb[k];

  float thr_y = (cb[3] - cb[1]) * 0.25f;
  float thr_x = (cb[2] - cb[0]) * 0.25f;
  float bo[4];
#pragma unroll
  for (int j = 0; j < 4; ++j) {
    float thr = (j & 1) ? thr_x : thr_y;
    float b = pr[4 + j];
    float extra = fmaxf(b - thr, 0.f) + fminf(b + thr, 0.f);
    bo[j] = b - extra;
  }
  float cx = 0.5f * (cb[0] + cb[2]);
  float cy = 0.5f * (cb[1] + cb[3]);
  float bp[8] = {cb[0], cy + bo[0], cx + bo[1], cb[1],
                 cb[2], cy + bo[2], cx + bo[3], cb[3]};

  int nbase = n * P;
  int nbaseLo = n * (100 * 152);
  float rb[4];
#pragma unroll
  for (int pt = 0; pt < 4; ++pt) {
    float hi = samp48(part, Mtot, nbase, W, H, bp[2 * pt], bp[2 * pt + 1],
                      DYN_CH + pt);
    float val;
    if (level == 0) {
      val = hi;
    } else {
      float lo = 0.5f * samp48(part_lo, MtotLo, nbaseLo, 152, 100,
                               bp[2 * pt] * 2.f, bp[2 * pt + 1] * 2.f,
                               DYN_CH + pt);
      float e0 = pr[26 + 2 * pt], e1 = pr[26 + 2 * pt + 1];
      float mx = fmaxf(e0, e1);
      float w0 = expf(e0 - mx), w1 = expf(e1 - mx);
      val = (lo * w0 + hi * w1) / (w0 + w1);
    }
    rb[pt] = val;
  }
  float* orb = out_regbox + (size_t)n * 4 * P + p;
  orb[0] = bp[0] + rb[0];
  orb[(size_t)P] = bp[3] + rb[1];
  orb[(size_t)2 * P] = bp[4] + rb[2];
  orb[(size_t)3 * P] = bp[7] + rb[3];

  float sx[9] = {cb[0], cb[0], cb[0], cx, cx, cx, cb[2], cb[2], cb[2]};
  float sy[9] = {cb[1], cy, cb[3], cb[1], cy, cb[3], cb[1], cy, cb[3]};
  float* sw = sem_ws + ((size_t)n * P + p) * 18;
#pragma unroll
  for (int k = 0; k < 9; ++k) {
    sw[2 * k] = sx[k] + pr[8 + 2 * k];
    sw[2 * k + 1] = sy[k] + pr[8 + 2 * k + 1];
  }
}

// ----------------------------- K4b: cls gather (64 lanes/pixel over 80 classes)
__global__ __launch_bounds__(256) void cls_gather(
    const __hip_bfloat16* __restrict__ map, const float* __restrict__ sem_ws,
    const float* __restrict__ bias, float* __restrict__ out, int H, int W,
    int P) {
  int lane = threadIdx.x & 63;
  int pix = blockIdx.x * 4 + (threadIdx.x >> 6);
  int n = blockIdx.y;
  if (pix >= P) return;
  const float* sp = sem_ws + ((size_t)n * P + pix) * 18;
  float acc0 = 0.f, acc1 = 0.f;
  const __hip_bfloat16* mb = map + (size_t)n * P * CLS_CH;
#pragma unroll
  for (int pt = 0; pt < 9; ++pt) {
    float px = sp[2 * pt], py = sp[2 * pt + 1];
    float xc = fminf(fmaxf(px, 0.f), (float)(W - 1));
    float yc = fminf(fmaxf(py, 0.f), (float)(H - 1));
    float x0f = floorf(xc), y0f = floorf(yc);
    float fx = xc - x0f, fy = yc - y0f;
    int x0 = (int)x0f, y0 = (int)y0f;
    int x1 = min(x0 + 1, W - 1), y1 = min(y0 + 1, H - 1);
    float w00 = (1.f - fx) * (1.f - fy), w01 = fx * (1.f - fy);
    float w10 = (1.f - fx) * fy, w11 = fx * fy;
    const __hip_bfloat16* c00 = mb + (size_t)(y0 * W + x0) * CLS_CH + pt * 80;
    const __hip_bfloat16* c01 = mb + (size_t)(y0 * W + x1) * CLS_CH + pt * 80;
    const __hip_bfloat16* c10 = mb + (size_t)(y1 * W + x0) * CLS_CH + pt * 80;
    const __hip_bfloat16* c11 = mb + (size_t)(y1 * W + x1) * CLS_CH + pt * 80;
    acc0 += w00 * __bfloat162float(c00[lane]) + w01 * __bfloat162float(c01[lane]) +
            w10 * __bfloat162float(c10[lane]) + w11 * __bfloat162float(c11[lane]);
    if (lane < 16)
      acc1 += w00 * __bfloat162float(c00[lane + 64]) +
              w01 * __bfloat162float(c01[lane + 64]) +
              w10 * __bfloat162float(c10[lane + 64]) +
              w11 * __bfloat162float(c11[lane + 64]);
  }
  float* on = out + (size_t)n * NUM_CLASSES * P + pix;
  on[(size_t)lane * P] = acc0 + bias[lane];
  if (lane < 16) on[(size_t)(lane + 64) * P] = acc1 + bias[lane + 64];
}

// ---------------------------------------------------------------------- launch
extern "C" void kernel_launch(void* const* d_in, const int* in_sizes, int n_in,
                              void* d_out, int out_size, void* d_ws,
                              size_t ws_size, hipStream_t stream) {
  const float* reg_feat0 = (const float*)d_in[0];
  const float* reg_feat1 = (const float*)d_in[1];
  const float* cls_feat0 = (const float*)d_in[2];
  const float* cls_feat1 = (const float*)d_in[3];
  const float* anchor0 = (const float*)d_in[4];
  const float* anchor1 = (const float*)d_in[5];
  const float* dyn_w = (const float*)d_in[6];
  const float* dyn_b = (const float*)d_in[7];
  const float* reg_w = (const float*)d_in[8];
  const float* cls_w = (const float*)d_in[9];
  const float* cls_b = (const float*)d_in[10];

  const int P0 = 15200, P1 = 3800;
  const int M0 = N_BATCH * P0;          // 30400
  const int M1 = N_BATCH * P1;          // 7600
  const int MT0 = (M0 + 255) / 256;     // 119 (cls 256-tiles)
  const int MT1 = (M1 + 255) / 256;     // 30
  const int CT0 = (M0 + 63) / 64;       // 475 (conv 64-tiles)
  const int CT1 = (M1 + 63) / 64;       // 119

  float* out = (float*)d_out;
  float* out_cls0 = out;
  float* out_cls1 = out_cls0 + (size_t)N_BATCH * NUM_CLASSES * P0;
  float* out_coarse0 = out_cls1 + (size_t)N_BATCH * NUM_CLASSES * P1;
  float* out_coarse1 = out_coarse0 + (size_t)N_BATCH * 4 * P0;
  float* out_reg0 = out_coarse1 + (size_t)N_BATCH * 4 * P1;
  float* out_reg1 = out_reg0 + (size_t)N_BATCH * 4 * P0;

  // ---- workspace layout (bytes)
  char* w = (char*)d_ws;
  float* semb = (float*)w;                         w += 2188800;   // 2*15200*18 f
  __hip_bfloat16* bpack = (__hip_bfloat16*)w;      w += 368640;    // cls W
  __hip_bfloat16* wpack = (__hip_bfloat16*)w;      w += 221184;    // dyn+reg W
  __hip_bfloat16* apack = (__hip_bfloat16*)w;      w += 15564800;  // cls A (L0 max)
  __hip_bfloat16* rpack = (__hip_bfloat16*)w;      w += 15564800;  // conv A (L0 max)
  float* part0 = (float*)w;                        w += 17510400;  // 3*30400*48 f
  float* part1 = (float*)(((char*)rpack) + 4194304);  // alias: rpack L1 uses 3.9MB
  __hip_bfloat16* clsmap = (__hip_bfloat16*)w;     w += 43776000;  // [m][720] bf16

  hipLaunchKernelGGL(pack_b, dim3(90), dim3(256), 0, stream, cls_w, bpack);
  hipLaunchKernelGGL(pack_w, dim3(54), dim3(256), 0, stream, dyn_w, reg_w, wpack);

  // ---- level 0
  hipLaunchKernelGGL(pack_a, dim3(MT0 * 32), dim3(256), 0, stream, cls_feat0,
                     apack, P0, M0);
  hipLaunchKernelGGL(cls_gemm_mfma, dim3(MT0, 9), dim3(256), 0, stream,
                     (const uint4*)apack, (const uint4*)bpack, clsmap, M0);
  hipLaunchKernelGGL(pack_row, dim3(MT0 * 32), dim3(256), 0, stream, reg_feat0,
                     rpack, P0, M0);
  hipLaunchKernelGGL(dyn_reg_conv_mfma, dim3(CT0, 3), dim3(256), 0, stream,
                     (const uint4*)rpack, (const uint4*)wpack, part0, M0, P0,
                     152, 100);
  hipLaunchKernelGGL(decode, dim3((P0 + 255) / 256, N_BATCH), dim3(256), 0,
                     stream, part0, part0, dyn_b, anchor0, out_coarse0, out_reg0,
                     semb, M0, M0, 100, 152, P0, 0);
  hipLaunchKernelGGL(cls_gather, dim3((P0 + 3) / 4, N_BATCH), dim3(256), 0,
                     stream, clsmap, semb, cls_b, out_cls0, 100, 152, P0);

  // ---- level 1
  hipLaunchKernelGGL(pack_a, dim3(MT1 * 32), dim3(256), 0, stream, cls_feat1,
                     apack, P1, M1);
  hipLaunchKernelGGL(cls_gemm_mfma, dim3(MT1, 9), dim3(256), 0, stream,
                     (const uint4*)apack, (const uint4*)bpack, clsmap, M1);
  hipLaunchKernelGGL(pack_row, dim3(MT1 * 32), dim3(256), 0, stream, reg_feat1,
                     rpack, P1, M1);
  hipLaunchKernelGGL(dyn_reg_conv_mfma, dim3(CT1, 3), dim3(256), 0, stream,
                     (const uint4*)rpack, (const uint4*)wpack, part1, M1, P1,
                     76, 50);
  hipLaunchKernelGGL(decode, dim3((P1 + 255) / 256, N_BATCH), dim3(256), 0,
                     stream, part1, part0, dyn_b, anchor1, out_coarse1, out_reg1,
                     semb, M1, M0, 50, 76, P1, 1);
  hipLaunchKernelGGL(cls_gather, dim3((P1 + 3) / 4, N_BATCH), dim3(256), 0,
                     stream, clsmap, semb, cls_b, out_cls1, 50, 76, P1);
}